// Round 3
// baseline (263.148 us; speedup 1.0000x reference)
//
#include <hip/hip_runtime.h>
#include <hip/hip_bf16.h>

typedef __attribute__((ext_vector_type(8))) short short8;
typedef __attribute__((ext_vector_type(4))) short short4v;
typedef __attribute__((ext_vector_type(4))) float f32x4;
typedef __attribute__((ext_vector_type(4))) unsigned uint4v;
typedef __attribute__((ext_vector_type(2))) unsigned uint2v;

#define MFMA16(a, b, c) __builtin_amdgcn_mfma_f32_16x16x32_bf16(a, b, c, 0, 0, 0)

// round-to-nearest-even f32 -> bf16 bit pattern
__device__ __forceinline__ short f2bf(float f) {
    union { float f; unsigned u; } v; v.f = f;
    unsigned r = v.u + 0x7fffu + ((v.u >> 16) & 1u);
    return (short)(r >> 16);
}
__device__ __forceinline__ unsigned pack2(float lo, float hi) {
    return ((unsigned)(unsigned short)f2bf(hi) << 16) |
           (unsigned)(unsigned short)f2bf(lo);
}

// ---------------------------------------------------------------------------
// Kernel 0: convert concatenated [Wq;Wk;Wv] (768x256 f32) to bf16.
// ---------------------------------------------------------------------------
__global__ __launch_bounds__(256) void wconv(
    const float* __restrict__ Wq, const float* __restrict__ Wk,
    const float* __restrict__ Wv, short* __restrict__ Wb)
{
    int e = (blockIdx.x * 256 + threadIdx.x) * 8;
    const float* p = (e < 65536) ? (Wq + e)
                   : (e < 131072) ? (Wk + (e - 65536))
                                  : (Wv + (e - 131072));
    float4 a = *(const float4*)p;
    float4 b = *(const float4*)(p + 4);
    short8 h = { f2bf(a.x), f2bf(a.y), f2bf(a.z), f2bf(a.w),
                 f2bf(b.x), f2bf(b.y), f2bf(b.z), f2bf(b.w) };
    *(short8*)(Wb + e) = h;
}

// ---------------------------------------------------------------------------
// Kernel 1: QKV projection (unchanged from round 2).
// ---------------------------------------------------------------------------
__global__ __launch_bounds__(256) void qkv_proj(
    const float* __restrict__ x, const short* __restrict__ Wb,
    const float* __restrict__ bq, const float* __restrict__ bk,
    const float* __restrict__ bv,
    short* __restrict__ Qb, short* __restrict__ Kb, short* __restrict__ VTg)
{
    __shared__ short xs[64 * 264];
    __shared__ short wsS[64 * 264];

    const int tid = threadIdx.x;
    const int wid = tid >> 6;
    const int l   = tid & 63;
    const int l15 = l & 15, lg = l >> 4;
    const int r0  = blockIdx.x * 64;
    const int cg  = blockIdx.y;

    {
        const float4* src = (const float4*)(x + (size_t)r0 * 256);
        #pragma unroll
        for (int p = 0; p < 16; ++p) {
            float4 v = src[p * 256 + tid];
            int idx = (p * 256 + tid) * 4;
            int row = idx >> 8, col = idx & 255;
            short4v h = { f2bf(v.x), f2bf(v.y), f2bf(v.z), f2bf(v.w) };
            *(short4v*)&xs[row * 264 + col] = h;
        }
    }

    short8 wreg[8];
    {
        const short8* wsrc = (const short8*)(Wb + (size_t)(cg * 3) * 64 * 256);
        #pragma unroll
        for (int p = 0; p < 8; ++p) wreg[p] = wsrc[p * 256 + tid];
    }
    __syncthreads();

    short8 afr[8];
    {
        const int arow = wid * 16 + l15;
        #pragma unroll
        for (int ks = 0; ks < 8; ++ks)
            afr[ks] = *(const short8*)&xs[arow * 264 + ks * 32 + lg * 8];
    }

    const float* bm[3] = { bq, bk, bv };

    for (int c = 0; c < 3; ++c) {
        const int gc  = cg * 3 + c;
        const int m   = gc >> 2;
        const int wr0 = (gc & 3) * 64;

        #pragma unroll
        for (int p = 0; p < 8; ++p) {
            int idx8 = p * 256 + tid;
            int row = idx8 >> 5, col = (idx8 & 31) * 8;
            *(short8*)&wsS[row * 264 + col] = wreg[p];
        }
        __syncthreads();

        if (c < 2) {
            const short8* wsrc =
                (const short8*)(Wb + (size_t)(gc + 1) * 64 * 256);
            #pragma unroll
            for (int p = 0; p < 8; ++p) wreg[p] = wsrc[p * 256 + tid];
        }

        f32x4 acc[4] = {};
        #pragma unroll
        for (int n = 0; n < 4; ++n) {
            const short* kr = &wsS[(n * 16 + l15) * 264 + lg * 8];
            #pragma unroll
            for (int ks = 0; ks < 8; ++ks) {
                short8 bfr = *(const short8*)(kr + ks * 32);
                acc[n] = MFMA16(afr[ks], bfr, acc[n]);
            }
        }

        const int rowbase = r0 + wid * 16 + (lg << 2);
        #pragma unroll
        for (int n = 0; n < 4; ++n) {
            const int col   = wr0 + n * 16 + l15;
            const float bias = bm[m][col];
            #pragma unroll
            for (int j = 0; j < 4; ++j) {
                const int grow = rowbase + j;
                short hv = f2bf(acc[n][j] + bias);
                if (m == 0)      Qb[(size_t)grow * 256 + col] = hv;
                else if (m == 1) Kb[(size_t)grow * 256 + col] = hv;
                else {
                    int bb = grow >> 12, tt = grow & 4095;
                    VTg[(size_t)bb * (256 * 4096) + (size_t)col * 4096 + tt] = hv;
                }
            }
        }
        __syncthreads();
    }
}

// ---------------------------------------------------------------------------
// Kernel 2: causal flash attention, swapped-QK^T in-register softmax.
//   grid 512 blocks (heavy-first LPT decode), 512 thr = 8 waves.
//   Block: 32 Q-rows (2 row-groups x 16), 4-way kt parity split.
//   Wave wid: rg = wid&1, par = wid>>1; computes kt = 4*si + par.
//   K in LDS (4 buffers), staged via asm-forced reg prefetch (T14).
//   V read direct from global VTg (L2-resident) as PV A-fragments.
//   S^T = mfma(K,Q): lane owns q-row l15; softmax fully per-lane scalars.
//   P -> PV B-frags via packed 8-word per-wave LDS exchange (no barrier).
// ---------------------------------------------------------------------------
__global__ __launch_bounds__(512) void attn_fwd(
    const short* __restrict__ Qb, const short* __restrict__ Kb,
    const short* __restrict__ VTg, float* __restrict__ out)
{
    __shared__ short    Ks[4][64 * 264];   // 4 x 33.8 KB = 135.2 KB
    __shared__ unsigned Px[8][64 * 12];    // per-wave P exchange, 24.6 KB

    const int tid = threadIdx.x;
    const int wid = tid >> 6;
    const int l   = tid & 63;
    const int l15 = l & 15, lg = l >> 4;
    const int rg  = wid & 1;           // row-group 0..1 (16 rows each)
    const int par = wid >> 1;          // kt parity 0..3
    const int tl  = tid >> 7;          // staging tile 0..3
    const int tt  = tid & 127;         // staging thread-in-tile

    // LPT decode: heaviest row-blocks dispatched first
    const int idx    = blockIdx.x;
    const int rowblk = 127 - (idx >> 2);
    const int b      = idx & 3;
    const int qtmax  = (rowblk * 32 + 31) >> 6;     // last kt tile
    const int nsi    = (qtmax >> 2) + 1;

    const short* KbB  = Kb  + (size_t)b * 4096 * 256;
    const short* VTgB = VTg + (size_t)b * (256 * 4096);

    // Q fragments: B-operand, rows rowblk*32 + rg*16 + l15
    const int qrow_loc = rg * 16 + l15;              // row within block
    const int qrow_g   = rowblk * 32 + qrow_loc;     // global row in batch
    short8 aq[8];
    {
        const short* qrow = Qb + ((size_t)(b * 4096 + qrow_g)) * 256 + lg * 8;
        #pragma unroll
        for (int ks = 0; ks < 8; ++ks)
            aq[ks] = *(const short8*)(qrow + ks * 32);
    }

    f32x4 kreg[16];
    bool validW;

#define PREFETCH(SI) do {                                                   \
        int kt4 = 4 * (SI) + tl;                                            \
        validW = (kt4 <= qtmax);                                            \
        if (validW) {                                                       \
            const short* gsrc = KbB + ((size_t)(kt4 * 64) << 8);            \
            _Pragma("unroll")                                               \
            for (int p = 0; p < 16; ++p) {                                  \
                const short* ga = gsrc + (p * 128 + tt) * 8;                \
                asm volatile("global_load_dwordx4 %0, %1, off"              \
                             : "=v"(kreg[p]) : "v"(ga) : "memory");         \
            }                                                               \
        }                                                                   \
    } while (0)

    PREFETCH(0);

    f32x4 o[16] = {};
    float mrow = -INFINITY;
    float srow = 0.f;

    // local row within the 64-row causal block (for diagonal masking)
    const int rowloc64 = ((rowblk & 1) << 5) + qrow_loc;

    for (int si = 0; si < nsi; ++si) {
        __syncthreads();   // prior compute's Ks reads done

        asm volatile("s_waitcnt vmcnt(0)" ::: "memory");
        if (validW) {
            #pragma unroll
            for (int p = 0; p < 16; ++p) {
                int idx16 = p * 128 + tt;
                *(f32x4*)&Ks[tl][idx16 * 8 + (idx16 >> 5) * 8] = kreg[p];
            }
        }
        __syncthreads();   // staged ready

        if (si + 1 < nsi) PREFETCH(si + 1);
        else validW = false;

        const int kt = 4 * si + par;
        if (kt > qtmax) continue;

        // S^T = K * Q : lane holds S[qrow=l15][key = n*16 + lg*4 + j]
        f32x4 s[4] = {};
        #pragma unroll
        for (int n = 0; n < 4; ++n) {
            const short* kr = &Ks[par][(n * 16 + l15) * 264 + lg * 8];
            #pragma unroll
            for (int ks = 0; ks < 8; ++ks) {
                short8 kfr = *(const short8*)(kr + ks * 32);
                s[n] = MFMA16(kfr, aq[ks], s[n]);
            }
        }

        // scale + causal mask (diag tile only) + in-lane max
        const bool diag = (kt == qtmax);
        float pmax = -INFINITY;
        #pragma unroll
        for (int n = 0; n < 4; ++n)
            #pragma unroll
            for (int j = 0; j < 4; ++j) {
                float v = s[n][j] * 0.0625f;   // 1/sqrt(256)
                if (diag) {
                    int keyloc = n * 16 + lg * 4 + j;
                    if (keyloc > rowloc64) v = -INFINITY;
                }
                s[n][j] = v;
                pmax = fmaxf(pmax, v);
            }
        // full row max across the 4 partner lanes (same l15)
        pmax = fmaxf(pmax, __shfl_xor(pmax, 16, 64));
        pmax = fmaxf(pmax, __shfl_xor(pmax, 32, 64));

        const float mn = fmaxf(mrow, pmax);
        const float f  = __expf(mrow - mn);    // 0 on first tile
        mrow = mn;

        // P = exp(s - m), per-lane partial row sum, pack to bf16 words
        float ps = 0.f;
        unsigned W[8];
        #pragma unroll
        for (int n = 0; n < 4; ++n) {
            float p0 = __expf(s[n][0] - mn);
            float p1 = __expf(s[n][1] - mn);
            float p2 = __expf(s[n][2] - mn);
            float p3 = __expf(s[n][3] - mn);
            ps += (p0 + p1) + (p2 + p3);
            W[n * 2 + 0] = pack2(p0, p1);
            W[n * 2 + 1] = pack2(p2, p3);
        }
        srow = srow * f + ps;

        // exchange: lane writes its 8 words, reads B-frags for PV
        *(uint4v*)&Px[wid][l * 12 + 0] = uint4v{ W[0], W[1], W[2], W[3] };
        *(uint4v*)&Px[wid][l * 12 + 4] = uint4v{ W[4], W[5], W[6], W[7] };
        asm volatile("s_waitcnt lgkmcnt(0)" ::: "memory");

        const int srcA = l15 + ((lg & 1) << 5);   // partner lane lg'=2(lg&1)
        const int srcB = srcA + 16;
        short8 pb[2];
        #pragma unroll
        for (int ks2 = 0; ks2 < 2; ++ks2) {
            const int n = 2 * ks2 + (lg >> 1);
            uint2v a = *(uint2v*)&Px[wid][srcA * 12 + 2 * n];
            uint2v c = *(uint2v*)&Px[wid][srcB * 12 + 2 * n];
            union { uint4v u; short8 s; } cvt;
            cvt.u = uint4v{ a[0], a[1], c[0], c[1] };
            pb[ks2] = cvt.s;
        }

        // rescale O^T (lane-scalar f)
        #pragma unroll
        for (int dt = 0; dt < 16; ++dt)
            #pragma unroll
            for (int j = 0; j < 4; ++j)
                o[dt][j] *= f;

        // O^T += V^T * P^T ; V^T A-frags direct from global (L2-resident)
        const short* vbase = VTgB + (size_t)l15 * 4096 + kt * 64 + lg * 8;
        #pragma unroll
        for (int ks2 = 0; ks2 < 2; ++ks2) {
            #pragma unroll
            for (int dt = 0; dt < 16; ++dt) {
                short8 va = *(const short8*)(vbase + (size_t)dt * 16 * 4096 +
                                             ks2 * 32);
                o[dt] = MFMA16(va, pb[ks2], o[dt]);
            }
        }
    }

    // finalize row sum across partner lanes
    srow += __shfl_xor(srow, 16, 64);
    srow += __shfl_xor(srow, 32, 64);

    // 4-way parity merge via LDS (reuse Ks as f32 scratch)
    __syncthreads();
    float* scr = (float*)&Ks[0][0];        // [3][32][256] f32 = 96 KB
    float* ms  = (float*)&Px[0][0];        // [3][32][2]

    if (par != 0) {
        const int pi = par - 1;
        #pragma unroll
        for (int dt = 0; dt < 16; ++dt)
            *(f32x4*)&scr[(pi * 32 + qrow_loc) * 256 + dt * 16 + lg * 4] = o[dt];
        if (lg == 0) {
            ms[(pi * 32 + qrow_loc) * 2 + 0] = mrow;
            ms[(pi * 32 + qrow_loc) * 2 + 1] = srow;
        }
    }
    __syncthreads();
    if (par == 0) {
        float m1 = ms[(0 * 32 + qrow_loc) * 2 + 0];
        float s1 = ms[(0 * 32 + qrow_loc) * 2 + 1];
        float m2 = ms[(1 * 32 + qrow_loc) * 2 + 0];
        float s2 = ms[(1 * 32 + qrow_loc) * 2 + 1];
        float m3 = ms[(2 * 32 + qrow_loc) * 2 + 0];
        float s3 = ms[(2 * 32 + qrow_loc) * 2 + 1];
        float M  = fmaxf(fmaxf(mrow, m1), fmaxf(m2, m3));
        float w0 = __expf(mrow - M), w1 = __expf(m1 - M);
        float w2 = __expf(m2 - M),  w3 = __expf(m3 - M);
        float rs = 1.f / (srow * w0 + s1 * w1 + s2 * w2 + s3 * w3);

        float* og = out + ((size_t)(b * 4096 + qrow_g)) * 256;
        #pragma unroll
        for (int dt = 0; dt < 16; ++dt) {
            f32x4 o1 = *(f32x4*)&scr[(0 * 32 + qrow_loc) * 256 + dt * 16 + lg * 4];
            f32x4 o2 = *(f32x4*)&scr[(1 * 32 + qrow_loc) * 256 + dt * 16 + lg * 4];
            f32x4 o3 = *(f32x4*)&scr[(2 * 32 + qrow_loc) * 256 + dt * 16 + lg * 4];
            f32x4 r;
            #pragma unroll
            for (int j = 0; j < 4; ++j)
                r[j] = (o[dt][j] * w0 + o1[j] * w1 + o2[j] * w2 + o3[j] * w3) * rs;
            *(f32x4*)&og[dt * 16 + lg * 4] = r;
        }
    }
#undef PREFETCH
}

// ---------------------------------------------------------------------------
extern "C" void kernel_launch(void* const* d_in, const int* in_sizes, int n_in,
                              void* d_out, int out_size, void* d_ws, size_t ws_size,
                              hipStream_t stream) {
    const float* x  = (const float*)d_in[0];
    const float* Wq = (const float*)d_in[1];
    const float* bq = (const float*)d_in[2];
    const float* Wk = (const float*)d_in[3];
    const float* bk = (const float*)d_in[4];
    const float* Wv = (const float*)d_in[5];
    const float* bv = (const float*)d_in[6];

    short* Qb  = (short*)d_ws;                         // 8 MB
    short* Kb  = Qb + (size_t)16384 * 256;             // 8 MB
    short* VTg = Kb + (size_t)16384 * 256;             // 8 MB
    short* Wb  = VTg + (size_t)4 * 256 * 4096;         // 384 KB
    float* out = (float*)d_out;

    wconv<<<dim3(96), dim3(256), 0, stream>>>(Wq, Wk, Wv, Wb);
    qkv_proj<<<dim3(256, 4), dim3(256), 0, stream>>>(x, Wb, bq, bk, bv,
                                                     Qb, Kb, VTg);
    attn_fwd<<<dim3(512), dim3(512), 0, stream>>>(Qb, Kb, VTg, out);
}